// Round 7
// baseline (322.104 us; speedup 1.0000x reference)
//
#include <hip/hip_runtime.h>
#include <cstdint>
#include <cstddef>

#define HW 524288      // H*W = 512*1024
#define HW4 131072     // float4/int4 groups per channel
#define NBIN 1024      // lovasz error histogram bins over [0,2]

// ws layout (bytes):
//   0    : double acc[16][8]  {cnt,cx,cy,sx,sy,sxx,syy,seedfg}     1024 B
//   1024 : double seedbg[2]                                          16 B
//   1040 : float  lov[16]                                            64 B
//   1104 : u32    gctr                                                 4 B
//   1108 : u32    ctr2                                                 4 B
//   4096 : u32    gdump[2][256][8][NBIN] packed per-block hists 16777216 B
// memset range: [0, 1112)   (gdump fully overwritten, no zeroing)

__device__ __forceinline__ float wred(float v) {
#pragma unroll
  for (int o = 32; o > 0; o >>= 1) v += __shfl_xor(v, o, 64);
  return v;
}
__device__ __forceinline__ float fsig(float x) {
  return __builtin_amdgcn_rcpf(1.f + __expf(-x));
}
__device__ __forceinline__ float ftanh(float x) {
  return 1.f - 2.f * __builtin_amdgcn_rcpf(__expf(2.f * x) + 1.f);
}

// ---------------- pass1: masked per-instance sums only ----------------
// grid (512, B), 256 thr, 1 float4 group/thread (verified round-4 version).
__global__ __launch_bounds__(256) void pass1(
    const float* __restrict__ pred, const int* __restrict__ masks,
    double* __restrict__ acc)
{
  const int b = blockIdx.y;
  const int tid = threadIdx.x;
  const float4* pb4 = (const float4*)(pred + (size_t)b * 12 * HW);
  const int4*   mk4 = (const int4*)(masks + (size_t)b * 8 * HW);

  const int g = blockIdx.x * 256 + tid;          // max 512*256-1 = HW4-1  OK
  const int idx = g << 2;
  const int h = idx >> 10, w = idx & 1023;

  float4 p0 = pb4[g];
  float4 p1 = pb4[HW4 + g];
  float4 s0 = pb4[2 * HW4 + g];
  float4 s1 = pb4[3 * HW4 + g];
  int4 mv[8];
#pragma unroll
  for (int n = 0; n < 8; n++) mv[n] = mk4[n * HW4 + g];

  float p0v[4] = {p0.x, p0.y, p0.z, p0.w}, p1v[4] = {p1.x, p1.y, p1.z, p1.w};
  float s0v[4] = {s0.x, s0.y, s0.z, s0.w}, s1v[4] = {s1.x, s1.y, s1.z, s1.w};
  float exv[4], eyv[4];
#pragma unroll
  for (int j = 0; j < 4; j++) {
    exv[j] = ftanh(p0v[j]) + (float)((w + j) * (2.0 / 2047.0));
    eyv[j] = ftanh(p1v[j]) + (float)(h * (1.0 / 1023.0));
  }

  float c[8], cx[8], cy[8], sx[8], sy[8], sxx[8], syy[8];
#pragma unroll
  for (int n = 0; n < 8; n++) {
    c[n] = 0.f; cx[n] = 0.f; cy[n] = 0.f; sx[n] = 0.f; sy[n] = 0.f;
    sxx[n] = 0.f; syy[n] = 0.f;
    int mvv[4] = {mv[n].x, mv[n].y, mv[n].z, mv[n].w};
#pragma unroll
    for (int j = 0; j < 4; j++) {
      float mf = (mvv[j] > 0) ? 1.f : 0.f;
      c[n] += mf; cx[n] += mf * exv[j]; cy[n] += mf * eyv[j];
      sx[n] += mf * s0v[j]; sy[n] += mf * s1v[j];
      sxx[n] += mf * s0v[j] * s0v[j]; syy[n] += mf * s1v[j] * s1v[j];
    }
  }

  __shared__ float red[4][56];
  int lane = tid & 63, wid = tid >> 6;
#pragma unroll
  for (int n = 0; n < 8; n++) {
    float r0 = wred(c[n]),  r1 = wred(cx[n]), r2 = wred(cy[n]),
          r3 = wred(sx[n]), r4 = wred(sy[n]), r5 = wred(sxx[n]),
          r6 = wred(syy[n]);
    if (lane == 0) {
      red[wid][n * 7 + 0] = r0; red[wid][n * 7 + 1] = r1;
      red[wid][n * 7 + 2] = r2; red[wid][n * 7 + 3] = r3;
      red[wid][n * 7 + 4] = r4; red[wid][n * 7 + 5] = r5;
      red[wid][n * 7 + 6] = r6;
    }
  }
  __syncthreads();
  if (tid < 56) {
    float s = red[0][tid] + red[1][tid] + red[2][tid] + red[3][tid];
    int n = tid / 7, q = tid % 7;
    atomicAdd(&acc[((size_t)b * 8 + n) * 8 + q], (double)s);
  }
}

// ---- pass3f: pixel-major hist + dump + last-block Lovász + combine --------
// grid (256, B) = 512 blocks, 512 thr, 1 float4-group/thread -> 2048 px/blk;
// 256 blocks * 512 groups = HW4 exactly. 32 KB LDS -> 2 blocks/CU = 16
// waves/CU (round-6 regression was 1 block/CU = 8 waves/CU; latency-bound
// phase needs the waves). Per-instance params precomputed ONCE into LDS
// (no per-wave f64 divides in the loop). 8 waves staggered over 8 LDS
// hists. Non-atomic u16-packed dump (max 2048/field). Last 16 of 512
// arrivals (gctr) each reduce one seg's 256 partial hists + run the
// closed-form Lovász scan; last of those (ctr2) combines. Integer hist
// counts identical to verified rounds -> lovasz path bit-identical.
__global__ __launch_bounds__(512) void pass3f(
    const float* __restrict__ pred, const int* __restrict__ bbox,
    const int* __restrict__ masks, const int* __restrict__ cls_ids,
    double* __restrict__ acc, double* __restrict__ seedbg,
    float* __restrict__ lov, unsigned* __restrict__ gdump,
    unsigned* __restrict__ gctr, unsigned* __restrict__ ctr2,
    float* __restrict__ out)
{
  const int b = blockIdx.y;
  const int xb = blockIdx.x;                 // 0..255
  const int tid = threadIdx.x;
  const int lane = tid & 63, wid = tid >> 6; // 8 waves

  __shared__ __align__(16) unsigned hist[8 * NBIN];   // 32 KB, multi-purpose
  __shared__ float prm[8][4];
  __shared__ int   pcls[8];
  __shared__ float redf[8][9];
  __shared__ unsigned wcs[8], wps[8];
  __shared__ double sred[8];
  __shared__ unsigned oldsh;

  uint4* h4 = (uint4*)hist;
  for (int j = tid; j < 2048; j += 512) h4[j] = make_uint4(0u, 0u, 0u, 0u);
  // per-instance params: computed once per block (f64 work out of the loop)
  if (tid < 8) {
    const double* a = acc + ((size_t)b * 8 + tid) * 8;
    double a0 = a[0];
    double csd = a0 < 1.0 ? 1.0 : a0;
    prm[tid][0] = (float)(a[1] / csd);
    prm[tid][1] = (float)(a[2] / csd);
    prm[tid][2] = __expf((float)(a[3] / csd) * 10.f);
    prm[tid][3] = __expf((float)(a[4] / csd) * 10.f);
    pcls[tid] = cls_ids[b * 8 + tid];
  }
  __syncthreads();

  const float4* pb4 = (const float4*)(pred + (size_t)b * 12 * HW);
  const int4*   mk4 = (const int4*)(masks + (size_t)b * 8 * HW);
  const int4*   bb4 = (const int4*)(bbox + (size_t)b * 9 * HW);

  // g = xb*512 + tid  <=  255*512 + 511 = HW4-1  (in-bounds, exact cover)
  const int g = xb * 512 + tid;
  const int idx = g << 2;
  const int h = idx >> 10, w = idx & 1023;

  float4 p0 = pb4[g];
  float4 p1 = pb4[HW4 + g];
  float ex[4], ey[4];
  {
    float p0v[4] = {p0.x, p0.y, p0.z, p0.w}, p1v[4] = {p1.x, p1.y, p1.z, p1.w};
#pragma unroll
    for (int j = 0; j < 4; j++) {
      ex[j] = ftanh(p0v[j]) + (float)((w + j) * (2.0 / 2047.0));
      ey[j] = ftanh(p1v[j]) + (float)(h * (1.0 / 1023.0));
    }
  }

  float sbg = 0.f;
#pragma unroll
  for (int i = 0; i < 8; i++) {
    const int ni = (i + wid) & 7;   // 8 waves hit 8 different LDS hists
    float cxv = prm[ni][0], cyv = prm[ni][1];
    float sex = prm[ni][2], sey = prm[ni][3];
    int cls = __builtin_amdgcn_readfirstlane(pcls[ni]);
    int4   mv = mk4[(size_t)ni * HW4 + g];
    int4   bv = bb4[(size_t)(1 + ni) * HW4 + g];
    float4 sc = pb4[(size_t)(4 + cls) * HW4 + g];   // seed ch for cls
    float4 sb = pb4[(size_t)(4 + ni) * HW4 + g];    // bg-seed ch ni
    unsigned* hn = hist + ni * NBIN;
    int mvv[4] = {mv.x, mv.y, mv.z, mv.w}, bvv[4] = {bv.x, bv.y, bv.z, bv.w};
    float scv[4] = {sc.x, sc.y, sc.z, sc.w}, sbv[4] = {sb.x, sb.y, sb.z, sb.w};
    float sf = 0.f;
#pragma unroll
    for (int j = 0; j < 4; j++) {
      int m = (mvv[j] > 0) ? 1 : 0;
      float dx = ex[j] - cxv, dy = ey[j] - cyv;
      float d = __expf(-(dx * dx * sex + dy * dy * sey));
      float df = fsig(scv[j]) - d;
      sf += m ? df * df : 0.f;
      float s0 = fsig(sbv[j]);
      sbg += (bvv[j] == 0) ? s0 * s0 : 0.f;
      float e = m ? 2.f - 2.f * d : 2.f * d;
      int kbin = (int)(e * 512.f); kbin = kbin > (NBIN - 1) ? (NBIN - 1) : kbin;
      atomicAdd(&hn[kbin], m ? 65536u : 1u);   // max 2048/field fits u16
    }
    float r = wred(sf);
    if (lane == 0) redf[wid][ni] = r;
  }
  {
    float r = wred(sbg);
    if (lane == 0) redf[wid][8] = r;
  }
  __syncthreads();

  // non-atomic coalesced dump (fully overwritten) + tiny seed atomics
  {
    uint4* dst = (uint4*)(gdump + ((size_t)(b * 256 + xb) * 8) * NBIN);
    for (int j = tid; j < 2048; j += 512) dst[j] = h4[j];
    if (tid < 9) {
      float t = 0.f;
      for (int w2 = 0; w2 < 8; w2++) t += redf[w2][tid];
      if (tid < 8)
        atomicAdd(&acc[((size_t)b * 8 + tid) * 8 + 7], (double)t);
      else
        atomicAdd(&seedbg[b], (double)t);
    }
  }

  __threadfence();            // release: dump + seed atomics
  __syncthreads();
  if (tid == 0) oldsh = atomicAdd(gctr, 1u);
  __syncthreads();
  const unsigned old = oldsh;
  if (old < 496u) return;     // 512 total blocks; last 16 arrivals continue

  // ---------------- continuation: one seg per block ----------------
  const int seg = (int)(old - 496u);
  const int b2 = seg >> 3, n2 = seg & 7;
  __threadfence();            // acquire: all 512 dumps visible

  // reduce 256 partial hists; thread t owns bins t and t+512 (coalesced)
  unsigned ng0 = 0, ps0 = 0, ng1 = 0, ps1 = 0;
#pragma unroll 8
  for (int x2 = 0; x2 < 256; x2++) {
    const unsigned* src = gdump + (((size_t)(b2 * 256 + x2) * 8 + n2) << 10);
    unsigned v0 = src[tid], v1 = src[tid + 512];
    ng0 += v0 & 0xffffu; ps0 += v0 >> 16;
    ng1 += v1 & 0xffffu; ps1 += v1 >> 16;
  }
  __syncthreads();            // everyone done with old hist contents
  unsigned* mneg = hist;           // neg[1024]
  unsigned* mpos = hist + NBIN;    // pos[1024]
  mneg[tid] = ng0; mneg[tid + 512] = ng1;
  mpos[tid] = ps0; mpos[tid + 512] = ps1;
  __syncthreads();

  double G = acc[seg * 8 + 0];     // pass1-written (prior dispatch) - safe

  // descending-error scan: thread t owns bins {1023-2t, 1022-2t}
  int kk0 = (NBIN - 1) - tid * 2;
  unsigned h0n = mneg[kk0],     h0p = mpos[kk0];
  unsigned h1n = mneg[kk0 - 1], h1p = mpos[kk0 - 1];
  unsigned cntT = h0n + h0p + h1n + h1p, posT = h0p + h1p;
  unsigned ic = cntT, ip = posT;
  for (int o = 1; o < 64; o <<= 1) {
    unsigned yc = __shfl_up(ic, o, 64), yp = __shfl_up(ip, o, 64);
    if (lane >= o) { ic += yc; ip += yp; }
  }
  if (lane == 63) { wcs[wid] = ic; wps[wid] = ip; }
  __syncthreads();
  unsigned oc = 0, op = 0;
  for (int w2 = 0; w2 < wid; w2++) { oc += wcs[w2]; op += wps[w2]; }
  unsigned p = oc + ic - cntT, C = op + ip - posT;   // exclusive prefix

  double S = 0.0;
  {  // bin kk0
    double ec = (kk0 + 0.5) * (1.0 / 512.0);
    if (h0p) {
      S += (double)h0p * ec / (G + (double)(p - C));
      p += h0p; C += h0p;
    }
    if (h0n) {
      double rem = G - (double)C;
      if (rem > 0.0) {
        double aa = G + (double)(p - C);
        S += ec * rem * (1.0 / aa - 1.0 / (aa + (double)h0n));
      }
      p += h0n;
    }
  }
  {  // bin kk0-1
    double ec = (kk0 - 0.5) * (1.0 / 512.0);
    if (h1p) {
      S += (double)h1p * ec / (G + (double)(p - C));
      p += h1p; C += h1p;
    }
    if (h1n) {
      double rem = G - (double)C;
      if (rem > 0.0) {
        double aa = G + (double)(p - C);
        S += ec * rem * (1.0 / aa - 1.0 / (aa + (double)h1n));
      }
      p += h1n;
    }
  }
#pragma unroll
  for (int o = 32; o > 0; o >>= 1) S += __shfl_xor(S, o, 64);
  if (lane == 0) sred[wid] = S;
  __syncthreads();

  if (tid == 0) {
    double St = 0.0;
    for (int w2 = 0; w2 < 8; w2++) St += sred[w2];
    atomicExch(&lov[seg], (float)St);
    __threadfence();
    unsigned old2 = atomicAdd(ctr2, 1u);
    if (old2 == 15u) {               // last seg block: final combine
      __threadfence();
      const float FG[8] = {10.f, 10.f, 10.f, 40.f, 80.f, 100.f, 60.f, 20.f};
      double total = 0.0;
      for (int bb = 0; bb < 2; bb++) {
        double obj = 0, inst = 0, varl = 0, sfg = 0;
        for (int n = 0; n < 8; n++) {
          int s = bb * 8 + n;
          const double* a = acc + s * 8;
          double cnt = a[0];                       // pass1-written: safe plain
          double cs = cnt < 1.0 ? 1.0 : cnt;
          double smx = a[3] / cs, smy = a[4] / cs;
          double var = ((a[5] - cnt * smx * smx) + (a[6] - cnt * smy * smy)) /
                       (2.0 * cs);
          double v = (cnt >= 128.0) ? 1.0 : 0.0;
          // values mutated in THIS kernel: atomic reads (dodge stale XCD-L2)
          double sfv = atomicAdd((double*)&acc[s * 8 + 7], 0.0);
          double lv = (double)atomicAdd(&lov[s], 0.0f);
          obj += v;
          inst += lv * v;
          varl += var * v;
          sfg += (double)FG[cls_ids[s]] * sfv * v;
        }
        double objs = obj < 1.0 ? 1.0 : obj;
        double sbgv = atomicAdd((double*)&seedbg[bb], 0.0);
        double seedl = (sbgv + sfg) / (double)HW;
        total += inst / objs + 10.0 * (varl / objs) + seedl;
      }
      out[0] = (float)(0.5 * total);
    }
  }
}

extern "C" void kernel_launch(void* const* d_in, const int* in_sizes, int n_in,
                              void* d_out, int out_size, void* d_ws, size_t ws_size,
                              hipStream_t stream)
{
  (void)in_sizes; (void)n_in; (void)out_size; (void)ws_size;
  const float* pred  = (const float*)d_in[0];
  const int*   bbox  = (const int*)d_in[1];
  const int*   masks = (const int*)d_in[2];
  const int*   cls   = (const int*)d_in[3];

  char* ws = (char*)d_ws;
  double*   acc    = (double*)(ws + 0);       // 128 doubles
  double*   seedbg = (double*)(ws + 1024);    // 2 doubles
  float*    lov    = (float*)(ws + 1040);     // 16 floats
  unsigned* gctr   = (unsigned*)(ws + 1104);  // 1 u32
  unsigned* ctr2   = (unsigned*)(ws + 1108);  // 1 u32
  unsigned* gdump  = (unsigned*)(ws + 4096);  // 16 MB packed hists

  hipMemsetAsync(d_ws, 0, 1112, stream);
  pass1<<<dim3(512, 2), 256, 0, stream>>>(pred, masks, acc);
  pass3f<<<dim3(256, 2), 512, 0, stream>>>(pred, bbox, masks, cls, acc, seedbg,
                                           lov, gdump, gctr, ctr2, (float*)d_out);
}

// Round 8
// 199.353 us; speedup vs baseline: 1.6158x; 1.6158x over previous
//
#include <hip/hip_runtime.h>
#include <cstdint>
#include <cstddef>

#define HW 524288      // H*W = 512*1024
#define HW4 131072     // float4/int4 groups per channel
#define NBIN 1024      // lovasz error histogram bins over [0,2]

// ws layout (bytes):
//   0      : double acc[16][8]  {cnt,cx,cy,sx,sy,sxx,syy,seedfg}    1024 B
//   1024   : double seedbg[2]                                         16 B
//   1040   : float  lov[16]                                           64 B
//   1104   : u32    ctr3[16]  per-seg chunk-arrival counters          64 B
//   1168   : u32    ctr2      scanner counter                          4 B
//   4096   : u64    ghist[16][NBIN] (lo32=neg, hi32=pos)          131072 B
//   262144 : u32    gdump[2][256][8][NBIN] packed partial hists 16777216 B
// memset range: [0, 135168)   (gdump fully overwritten, no zeroing)
//
// Key lesson (R6/R7): NO __threadfence in blocks that have dirtied L2 —
// device-scope release forces a per-XCD dirty-L2 writeback; at 256-512
// blocks this serialized flush storm cost 60-120 us. pass3d therefore ends
// at the dump (dispatch boundary provides ordering); pass4c's fence is
// cheap because its only global writes are atomics (no dirty L2).

__device__ __forceinline__ float wred(float v) {
#pragma unroll
  for (int o = 32; o > 0; o >>= 1) v += __shfl_xor(v, o, 64);
  return v;
}
__device__ __forceinline__ float fsig(float x) {
  return __builtin_amdgcn_rcpf(1.f + __expf(-x));
}
__device__ __forceinline__ float ftanh(float x) {
  return 1.f - 2.f * __builtin_amdgcn_rcpf(__expf(2.f * x) + 1.f);
}

// ---------------- pass1: masked per-instance sums only ----------------
// grid (512, B), 256 thr, 1 float4 group/thread (verified round-4 version).
__global__ __launch_bounds__(256) void pass1(
    const float* __restrict__ pred, const int* __restrict__ masks,
    double* __restrict__ acc)
{
  const int b = blockIdx.y;
  const int tid = threadIdx.x;
  const float4* pb4 = (const float4*)(pred + (size_t)b * 12 * HW);
  const int4*   mk4 = (const int4*)(masks + (size_t)b * 8 * HW);

  const int g = blockIdx.x * 256 + tid;          // max 512*256-1 = HW4-1  OK
  const int idx = g << 2;
  const int h = idx >> 10, w = idx & 1023;

  float4 p0 = pb4[g];
  float4 p1 = pb4[HW4 + g];
  float4 s0 = pb4[2 * HW4 + g];
  float4 s1 = pb4[3 * HW4 + g];
  int4 mv[8];
#pragma unroll
  for (int n = 0; n < 8; n++) mv[n] = mk4[n * HW4 + g];

  float p0v[4] = {p0.x, p0.y, p0.z, p0.w}, p1v[4] = {p1.x, p1.y, p1.z, p1.w};
  float s0v[4] = {s0.x, s0.y, s0.z, s0.w}, s1v[4] = {s1.x, s1.y, s1.z, s1.w};
  float exv[4], eyv[4];
#pragma unroll
  for (int j = 0; j < 4; j++) {
    exv[j] = ftanh(p0v[j]) + (float)((w + j) * (2.0 / 2047.0));
    eyv[j] = ftanh(p1v[j]) + (float)(h * (1.0 / 1023.0));
  }

  float c[8], cx[8], cy[8], sx[8], sy[8], sxx[8], syy[8];
#pragma unroll
  for (int n = 0; n < 8; n++) {
    c[n] = 0.f; cx[n] = 0.f; cy[n] = 0.f; sx[n] = 0.f; sy[n] = 0.f;
    sxx[n] = 0.f; syy[n] = 0.f;
    int mvv[4] = {mv[n].x, mv[n].y, mv[n].z, mv[n].w};
#pragma unroll
    for (int j = 0; j < 4; j++) {
      float mf = (mvv[j] > 0) ? 1.f : 0.f;
      c[n] += mf; cx[n] += mf * exv[j]; cy[n] += mf * eyv[j];
      sx[n] += mf * s0v[j]; sy[n] += mf * s1v[j];
      sxx[n] += mf * s0v[j] * s0v[j]; syy[n] += mf * s1v[j] * s1v[j];
    }
  }

  __shared__ float red[4][56];
  int lane = tid & 63, wid = tid >> 6;
#pragma unroll
  for (int n = 0; n < 8; n++) {
    float r0 = wred(c[n]),  r1 = wred(cx[n]), r2 = wred(cy[n]),
          r3 = wred(sx[n]), r4 = wred(sy[n]), r5 = wred(sxx[n]),
          r6 = wred(syy[n]);
    if (lane == 0) {
      red[wid][n * 7 + 0] = r0; red[wid][n * 7 + 1] = r1;
      red[wid][n * 7 + 2] = r2; red[wid][n * 7 + 3] = r3;
      red[wid][n * 7 + 4] = r4; red[wid][n * 7 + 5] = r5;
      red[wid][n * 7 + 6] = r6;
    }
  }
  __syncthreads();
  if (tid < 56) {
    float s = red[0][tid] + red[1][tid] + red[2][tid] + red[3][tid];
    int n = tid / 7, q = tid % 7;
    atomicAdd(&acc[((size_t)b * 8 + n) * 8 + q], (double)s);
  }
}

// ---- pass3d: pixel-major hist + non-atomic dump (R2 structure, proven) ----
// grid (256, B) = 512 blocks, 512 thr, 1 float4-group/thread; 32 KB LDS ->
// 2 blocks/CU = 16 waves/CU. p0/p1 read once (tanh once). 8 waves staggered
// over 8 LDS hists. Per-instance params precomputed once into LDS. Ends at
// the dump: NO fence, NO counter (dispatch boundary orders pass4c).
__global__ __launch_bounds__(512) void pass3d(
    const float* __restrict__ pred, const int* __restrict__ bbox,
    const int* __restrict__ masks, const int* __restrict__ cls_ids,
    const double* __restrict__ acc, double* __restrict__ accw,
    double* __restrict__ seedbg, unsigned* __restrict__ gdump)
{
  const int b = blockIdx.y;
  const int xb = blockIdx.x;                 // 0..255
  const int tid = threadIdx.x;
  const int lane = tid & 63, wid = tid >> 6; // 8 waves

  __shared__ __align__(16) unsigned hist[8 * NBIN];   // 32 KB
  __shared__ float prm[8][4];
  __shared__ int   pcls[8];
  __shared__ float redf[8][9];

  uint4* h4 = (uint4*)hist;
  for (int j = tid; j < 2048; j += 512) h4[j] = make_uint4(0u, 0u, 0u, 0u);
  if (tid < 8) {   // per-instance params once per block
    const double* a = acc + ((size_t)b * 8 + tid) * 8;
    double a0 = a[0];
    double csd = a0 < 1.0 ? 1.0 : a0;
    prm[tid][0] = (float)(a[1] / csd);
    prm[tid][1] = (float)(a[2] / csd);
    prm[tid][2] = __expf((float)(a[3] / csd) * 10.f);
    prm[tid][3] = __expf((float)(a[4] / csd) * 10.f);
    pcls[tid] = cls_ids[b * 8 + tid];
  }
  __syncthreads();

  const float4* pb4 = (const float4*)(pred + (size_t)b * 12 * HW);
  const int4*   mk4 = (const int4*)(masks + (size_t)b * 8 * HW);
  const int4*   bb4 = (const int4*)(bbox + (size_t)b * 9 * HW);

  const int g = xb * 512 + tid;              // max 255*512+511 = HW4-1  OK
  const int idx = g << 2;
  const int h = idx >> 10, w = idx & 1023;

  float4 p0 = pb4[g];
  float4 p1 = pb4[HW4 + g];
  float ex[4], ey[4];
  {
    float p0v[4] = {p0.x, p0.y, p0.z, p0.w}, p1v[4] = {p1.x, p1.y, p1.z, p1.w};
#pragma unroll
    for (int j = 0; j < 4; j++) {
      ex[j] = ftanh(p0v[j]) + (float)((w + j) * (2.0 / 2047.0));
      ey[j] = ftanh(p1v[j]) + (float)(h * (1.0 / 1023.0));
    }
  }

  float sbg = 0.f;
#pragma unroll
  for (int i = 0; i < 8; i++) {
    const int ni = (i + wid) & 7;   // 8 waves hit 8 different LDS hists
    float cxv = prm[ni][0], cyv = prm[ni][1];
    float sex = prm[ni][2], sey = prm[ni][3];
    int cls = __builtin_amdgcn_readfirstlane(pcls[ni]);
    int4   mv = mk4[(size_t)ni * HW4 + g];
    int4   bv = bb4[(size_t)(1 + ni) * HW4 + g];
    float4 sc = pb4[(size_t)(4 + cls) * HW4 + g];   // seed ch for cls
    float4 sb = pb4[(size_t)(4 + ni) * HW4 + g];    // bg-seed ch ni
    unsigned* hn = hist + ni * NBIN;
    int mvv[4] = {mv.x, mv.y, mv.z, mv.w}, bvv[4] = {bv.x, bv.y, bv.z, bv.w};
    float scv[4] = {sc.x, sc.y, sc.z, sc.w}, sbv[4] = {sb.x, sb.y, sb.z, sb.w};
    float sf = 0.f;
#pragma unroll
    for (int j = 0; j < 4; j++) {
      int m = (mvv[j] > 0) ? 1 : 0;
      float dx = ex[j] - cxv, dy = ey[j] - cyv;
      float d = __expf(-(dx * dx * sex + dy * dy * sey));
      float df = fsig(scv[j]) - d;
      sf += m ? df * df : 0.f;
      float s0 = fsig(sbv[j]);
      sbg += (bvv[j] == 0) ? s0 * s0 : 0.f;
      float e = m ? 2.f - 2.f * d : 2.f * d;
      int kbin = (int)(e * 512.f); kbin = kbin > (NBIN - 1) ? (NBIN - 1) : kbin;
      atomicAdd(&hn[kbin], m ? 65536u : 1u);   // max 2048/field fits u16
    }
    float r = wred(sf);
    if (lane == 0) redf[wid][ni] = r;
  }
  {
    float r = wred(sbg);
    if (lane == 0) redf[wid][8] = r;
  }
  __syncthreads();

  // non-atomic coalesced dump (fully overwritten) + tiny seed atomics
  uint4* dst = (uint4*)(gdump + ((size_t)(b * 256 + xb) * 8) * NBIN);
  for (int j = tid; j < 2048; j += 512) dst[j] = h4[j];
  if (tid < 9) {
    float t = 0.f;
    for (int w2 = 0; w2 < 8; w2++) t += redf[w2][tid];
    if (tid < 8)
      atomicAdd(&accw[((size_t)b * 8 + tid) * 8 + 7], (double)t);
    else
      atomicAdd(&seedbg[b], (double)t);
  }
}

// ---- pass4c: chunk-reduce -> ghist atomics -> per-seg last-chunk scan -----
// 256 blocks (16 segs x 16 chunks) x 256 thr. Each block reduces 16 partial
// hists (R2 pass4a pattern) and u64-atomic-merges nonzero bins into ghist.
// Fence here is cheap: this kernel's only global writes are atomics (no
// dirty L2). Last-arriving chunk per seg (ctr3) reads ghist back via
// returning atomics (coherent) and runs the verified Lovász scan; last
// scanner (ctr2) runs the verified final combine.
__global__ __launch_bounds__(256) void pass4c(
    const unsigned* __restrict__ gdump, unsigned long long* __restrict__ ghist,
    const double* __restrict__ acc, const double* __restrict__ seedbg,
    const int* __restrict__ cls_ids, float* __restrict__ lov,
    unsigned* __restrict__ ctr3, unsigned* __restrict__ ctr2,
    float* __restrict__ out)
{
  const int seg = blockIdx.x >> 4;          // 0..15 = b*8+n
  const int chunk = blockIdx.x & 15;
  const int b2 = seg >> 3, n2 = seg & 7;
  const int tid = threadIdx.x;
  const int lane = tid & 63, wid = tid >> 6;
  __shared__ __align__(16) unsigned lh[NBIN * 2];   // [2k]=neg, [2k+1]=pos
  __shared__ unsigned wc[4], wp[4];
  __shared__ double sred[4];
  __shared__ unsigned oldsh;

  unsigned neg[4] = {0, 0, 0, 0}, pos[4] = {0, 0, 0, 0};
#pragma unroll
  for (int xb2 = 0; xb2 < 16; xb2++) {
    int blk = chunk * 16 + xb2;
    const uint4 v =
        ((const uint4*)gdump)[(((size_t)b2 * 256 + blk) * 8 + n2) * 256 + tid];
    neg[0] += v.x & 0xffffu; pos[0] += v.x >> 16;
    neg[1] += v.y & 0xffffu; pos[1] += v.y >> 16;
    neg[2] += v.z & 0xffffu; pos[2] += v.z >> 16;
    neg[3] += v.w & 0xffffu; pos[3] += v.w >> 16;
  }
  unsigned long long* gh = ghist + (size_t)seg * NBIN;
#pragma unroll
  for (int i = 0; i < 4; i++) {
    if (neg[i] | pos[i])
      atomicAdd(&gh[tid * 4 + i],
                (unsigned long long)neg[i] | ((unsigned long long)pos[i] << 32));
  }

  __threadfence();            // cheap: no dirty L2 in this kernel
  __syncthreads();
  if (tid == 0) oldsh = atomicAdd(&ctr3[seg], 1u);
  __syncthreads();
  if (oldsh != 15u) return;   // only the last chunk block of this seg scans

  // coherent read-back of the full seg hist (returning atomics)
#pragma unroll
  for (int i = 0; i < 4; i++) {
    unsigned long long v = atomicAdd(&gh[tid * 4 + i], 0ULL);
    lh[2 * (tid * 4 + i)]     = (unsigned)(v & 0xffffffffULL);
    lh[2 * (tid * 4 + i) + 1] = (unsigned)(v >> 32);
  }
  __syncthreads();

  double G = acc[seg * 8 + 0];   // pass1-written (prior dispatch): safe plain

  unsigned cntT = 0, posT = 0;
#pragma unroll
  for (int i = 0; i < 4; i++) {
    int kk = (NBIN - 1) - tid * 4 - i;
    unsigned h0 = lh[2 * kk], h1 = lh[2 * kk + 1];
    cntT += h0 + h1; posT += h1;
  }
  unsigned ic = cntT, ip = posT;
  for (int o = 1; o < 64; o <<= 1) {
    unsigned yc = __shfl_up(ic, o, 64), yp = __shfl_up(ip, o, 64);
    if (lane >= o) { ic += yc; ip += yp; }
  }
  if (lane == 63) { wc[wid] = ic; wp[wid] = ip; }
  __syncthreads();
  unsigned oc = 0, op = 0;
  for (int w2 = 0; w2 < wid; w2++) { oc += wc[w2]; op += wp[w2]; }
  unsigned p = oc + ic - cntT, C = op + ip - posT;   // exclusive prefix

  double S = 0.0;
#pragma unroll
  for (int i = 0; i < 4; i++) {
    int kk = (NBIN - 1) - tid * 4 - i;
    unsigned n1 = lh[2 * kk + 1], n0 = lh[2 * kk];
    double ec = (kk + 0.5) * (1.0 / 512.0);   // bin-center error value
    if (n1) {
      S += (double)n1 * ec / (G + (double)(p - C));
      p += n1; C += n1;
    }
    if (n0) {
      double rem = G - (double)C;
      if (rem > 0.0) {
        double aa = G + (double)(p - C);
        S += ec * rem * (1.0 / aa - 1.0 / (aa + (double)n0));
      }
      p += n0;
    }
  }
#pragma unroll
  for (int o = 32; o > 0; o >>= 1) S += __shfl_xor(S, o, 64);
  if (lane == 0) sred[wid] = S;
  __syncthreads();

  if (tid == 0) {
    double St = sred[0] + sred[1] + sred[2] + sred[3];
    atomicExch(&lov[seg], (float)St);
    __threadfence();
    unsigned old2 = atomicAdd(ctr2, 1u);
    if (old2 == 15u) {               // last scanner: final combine
      __threadfence();
      const float FG[8] = {10.f, 10.f, 10.f, 40.f, 80.f, 100.f, 60.f, 20.f};
      double total = 0.0;
      for (int bb = 0; bb < 2; bb++) {
        double obj = 0, inst = 0, varl = 0, sfg = 0;
        for (int n = 0; n < 8; n++) {
          int s = bb * 8 + n;
          const double* a = acc + s * 8;
          double cnt = a[0];
          double cs = cnt < 1.0 ? 1.0 : cnt;
          double smx = a[3] / cs, smy = a[4] / cs;
          double var = ((a[5] - cnt * smx * smx) + (a[6] - cnt * smy * smy)) /
                       (2.0 * cs);
          double v = (cnt >= 128.0) ? 1.0 : 0.0;
          // acc[7]/seedbg written in pass3d (prior dispatch): plain reads OK.
          // lov written THIS dispatch by other blocks: atomic read.
          double lv = (double)atomicAdd(&lov[s], 0.0f);
          obj += v;
          inst += lv * v;
          varl += var * v;
          sfg += (double)FG[cls_ids[s]] * a[7] * v;
        }
        double objs = obj < 1.0 ? 1.0 : obj;
        double seedl = (seedbg[bb] + sfg) / (double)HW;
        total += inst / objs + 10.0 * (varl / objs) + seedl;
      }
      out[0] = (float)(0.5 * total);
    }
  }
}

extern "C" void kernel_launch(void* const* d_in, const int* in_sizes, int n_in,
                              void* d_out, int out_size, void* d_ws, size_t ws_size,
                              hipStream_t stream)
{
  (void)in_sizes; (void)n_in; (void)out_size; (void)ws_size;
  const float* pred  = (const float*)d_in[0];
  const int*   bbox  = (const int*)d_in[1];
  const int*   masks = (const int*)d_in[2];
  const int*   cls   = (const int*)d_in[3];

  char* ws = (char*)d_ws;
  double*             acc    = (double*)(ws + 0);       // 128 doubles
  double*             seedbg = (double*)(ws + 1024);    // 2 doubles
  float*              lov    = (float*)(ws + 1040);     // 16 floats
  unsigned*           ctr3   = (unsigned*)(ws + 1104);  // 16 u32
  unsigned*           ctr2   = (unsigned*)(ws + 1168);  // 1 u32
  unsigned long long* ghist  = (unsigned long long*)(ws + 4096);   // 128 KB
  unsigned*           gdump  = (unsigned*)(ws + 262144);           // 16 MB

  hipMemsetAsync(d_ws, 0, 135168, stream);
  pass1<<<dim3(512, 2), 256, 0, stream>>>(pred, masks, acc);
  pass3d<<<dim3(256, 2), 512, 0, stream>>>(pred, bbox, masks, cls, acc, acc,
                                           seedbg, gdump);
  pass4c<<<256, 256, 0, stream>>>(gdump, ghist, acc, seedbg, cls, lov,
                                  ctr3, ctr2, (float*)d_out);
}